// Round 14
// baseline (463.148 us; speedup 1.0000x reference)
//
#include <hip/hip_runtime.h>
#include <hip/hip_bf16.h>
#include <stdint.h>

typedef unsigned short u16;
typedef unsigned int u32;
typedef unsigned long long u64;
typedef __attribute__((ext_vector_type(8))) unsigned short u16x8;
typedef __attribute__((ext_vector_type(8))) short short8;
typedef __attribute__((ext_vector_type(4))) float f32x4;

#define CB   4
#define CC   256
#define CHW  4096
#define CNQ  4097
#define NQP  150
#define CHID 1024
#define XTROWS 4160   // 4096 img rows + exemplar + 63 zero pad (65 tiles of 64)
#define VROW   4160   // V cols padded to 65 tiles of 64

// ---------------- workspace layout (bytes) ----------------
#define XT_OFF   0ul                                        // bf16 [B][4160][256] swizzled
#define VB_OFF   (XT_OFF  + (size_t)CB*XTROWS*CC*2)         // bf16 [B][256][4160] swizzled
#define ST_OFF   (VB_OFF  + (size_t)CB*CC*VROW*2)           // bf16 [256][256] (S^T)
#define EXE_OFF  (ST_OFF  + 131072ul)                       // f32  [B][256] (unused slot)
#define ZL_OFF   (EXE_OFF + 4096ul)                         // f32  [B][256]  (S·em)
#define HEAT_OFF (ZL_OFF  + 4096ul)                         // f32  [B][4096]
#define QID_OFF  (HEAT_OFF+ 65536ul)                        // int  [B][160]
#define W1T_OFF  (QID_OFF + 2560ul)                         // f32  [257][1024]
#define W2T_OFF  (W1T_OFF + 1052672ul)                      // f32  [1024][257]
#define HB_OFF   (W2T_OFF + 1052672ul)                      // f32  [600][1024]
#define OP_OFF   (HB_OFF  + 2457600ul)                      // f32  [512][64][256] partial O
#define ML_OFF   (OP_OFF  + (size_t)512*64*256*4)           // f32  [512][64][2]   partial m,l

__device__ __forceinline__ u16 f2b(float f){
  __hip_bfloat16 h = __float2bfloat16(f); u16 r; __builtin_memcpy(&r, &h, 2); return r;
}
__device__ __forceinline__ f32x4 mfma16(u16x8 a, u16x8 b, f32x4 c){
  short8 as, bs; __builtin_memcpy(&as, &a, 16); __builtin_memcpy(&bs, &b, 16);
  return __builtin_amdgcn_mfma_f32_16x16x32_bf16(as, bs, c, 0, 0, 0);
}
__device__ __forceinline__ u16x8 zero8(){
  u16x8 v;
  #pragma unroll
  for (int e = 0; e < 8; e++) v[e] = 0;
  return v;
}
__device__ __forceinline__ u16x8 cvt8(f32x4 a, f32x4 b){
  u16x8 v;
  v[0]=f2b(a[0]); v[1]=f2b(a[1]); v[2]=f2b(a[2]); v[3]=f2b(a[3]);
  v[4]=f2b(b[0]); v[5]=f2b(b[1]); v[6]=f2b(b[2]); v[7]=f2b(b[3]);
  return v;
}
// async global->LDS, 16B per lane; LDS dest = wave-uniform base + lane*16
__device__ __forceinline__ void glds16(const u16* gp, u16* lp){
  __builtin_amdgcn_global_load_lds(
      (const __attribute__((address_space(1))) u32*)gp,
      (__attribute__((address_space(3))) u32*)lp, 16, 0, 0);
}

// ---- 16-lane reduce, pure-VALU DPP (row=16 lanes matches l15 groups) ----
#define DPPF(x, ctrl) __int_as_float(__builtin_amdgcn_mov_dpp(__float_as_int(x), (ctrl), 0xF, 0xF, true))
__device__ __forceinline__ float red16_max(float x){
  x = fmaxf(x, DPPF(x, 0xB1));   // quad_perm xor1
  x = fmaxf(x, DPPF(x, 0x4E));   // quad_perm xor2
  x = fmaxf(x, DPPF(x, 0x141));  // row_half_mirror
  x = fmaxf(x, DPPF(x, 0x140));  // row_mirror
  return x;
}
__device__ __forceinline__ float red16_sum(float x){
  x += DPPF(x, 0xB1);
  x += DPPF(x, 0x4E);
  x += DPPF(x, 0x141);
  x += DPPF(x, 0x140);
  return x;
}

// ---------------- shared helper bodies (block-uniform branch safe) -----------
__device__ __forceinline__ void tpose_body(const float* __restrict__ src,
    float* __restrict__ dst, int R, int C, int bx, int by, char* sbuf){
  float (*tile)[33] = (float(*)[33])sbuf;
  int c0 = bx*32, r0 = by*32;
  int tc = threadIdx.x & 31, tr = threadIdx.x >> 5;   // 8 rows per pass
  for (int i = tr; i < 32; i += 8){
    int r = r0 + i, c = c0 + tc;
    tile[i][tc] = (r < R && c < C) ? src[(long)r*C + c] : 0.f;
  }
  __syncthreads();
  for (int i = tr; i < 32; i += 8){
    int c = c0 + i, r = r0 + tc;
    if (c < C && r < R) dst[(long)c*R + r] = tile[tc][i];
  }
}

// 64x64 tiled transpose, f32 src -> bf16 dst; swz=1 bakes flash's K XOR swizzle.
// If vb != nullptr, ALSO emits the row-major group-swizzled Vb span (vconv fuse).
__device__ __forceinline__ void t64_body(const float* __restrict__ src,
    u16* __restrict__ dst, int srcLd, long srcBatch, int dstLd, long dstBatch,
    int swz, int bx, int by, int bz, char* sbuf, u16* __restrict__ vb){
  u16 (*tile)[72] = (u16(*)[72])sbuf;
  int c0 = bx*64, m0 = by*64;
  const float* S = src + (long)bz*srcBatch;
  u16* D = dst + (long)bz*dstBatch;
  int t = threadIdx.x;
  int r = t >> 2, q = t & 3;
  for (int uu = q; uu < 8; uu += 4){
    const float* p = S + (long)(c0+r)*srcLd + m0 + uu*8;
    f32x4 a0 = *(const f32x4*)p;
    f32x4 a1 = *(const f32x4*)(p + 4);
    *(u16x8*)&tile[r][uu*8] = cvt8(a0, a1);
  }
  __syncthreads();
  for (int uu = q; uu < 8; uu += 4){
    u16x8 v;
    #pragma unroll
    for (int e = 0; e < 8; e++) v[e] = tile[uu*8 + e][r];
    int gidx = (c0 >> 3) + uu;
    if (swz) gidx ^= (r & 7)*4;
    *(u16x8*)(D + (long)(m0+r)*dstLd + gidx*8) = v;
  }
  if (vb){
    int c = c0 + r, cx = c & 7;
    u16* drow = vb + ((long)bz*CC + c)*VROW + m0;
    #pragma unroll
    for (int uu = q; uu < 8; uu += 4){
      u16x8 v = *(const u16x8*)&tile[r][uu*8];
      *(u16x8*)(drow + (uu ^ cx)*8) = v;
    }
  }
}

// ---------------- K0 (merged): exe-prep + W1t/W2t transposes + St ------------
__global__ __launch_bounds__(256) void prep_k(
    const float* __restrict__ exe, const float* __restrict__ S,
    const float* __restrict__ W1, const float* __restrict__ W2,
    float* __restrict__ zl, u16* __restrict__ Xt, u16* __restrict__ Vb,
    u16* __restrict__ St, float* __restrict__ W1t, float* __restrict__ W2t){
  __shared__ __align__(16) char sbuf[9216];
  int id = blockIdx.x, t = threadIdx.x;
  if (id < 4){
    float* em = (float*)sbuf;
    int b = id;
    const float* p = exe + (b*CC + t)*49;
    float s = 0.f;
    for (int i = 0; i < 49; i++) s += p[i];
    float m = s / 49.f;
    em[t] = m;
    u16* xb = Xt + (size_t)b*XTROWS*CC;
    xb[(size_t)CHW*CC + t] = f2b(m);        // exemplar row (row&7==0: no swizzle)
    for (int i = 0; i < 63; i++)            // zero pad rows 4097..4159
      xb[(size_t)(CHW + 1 + i)*CC + t] = 0;
    {
      int cx = t & 7;
      u16* drow = Vb + ((long)b*CC + t)*VROW;
      #pragma unroll
      for (int gl = 0; gl < 8; gl++)
        *(u16x8*)(drow + (512 + gl)*8) = zero8();
      drow[(512 + cx)*8] = f2b(m);
    }
    __syncthreads();
    const float* Sr = S + (long)t*CC;
    float z = 0.f;
    for (int d = 0; d < CC; d++) z += Sr[d] * em[d];
    zl[b*CC + t] = z;
  } else if (id < 292){
    int i = id - 4;
    tpose_body(W1, W1t, CHID, 257, i % 9, i / 9, sbuf);
  } else if (id < 580){
    int i = id - 292;
    tpose_body(W2, W2t, 257, CHID, i % 32, i / 32, sbuf);
  } else {
    int i = id - 580;
    t64_body(S, St, CC, 0, CC, 0, 0, i & 3, i >> 2, 0, sbuf, nullptr);
  }
}

// ---------------- K1 (merged): img->(Xt + Vb) fused transpose + heat2 --------
__global__ __launch_bounds__(256) void big_k(
    const float* __restrict__ img, const float* __restrict__ zl,
    u16* __restrict__ Xt, u16* __restrict__ Vb,
    float* __restrict__ heat, float* __restrict__ out_img){
  __shared__ __align__(16) char sbuf[9216];
  int id = blockIdx.x, t = threadIdx.x;
  if (id < 1024){
    int bx = id & 3, by = (id >> 2) & 63, bz = id >> 8;
    t64_body(img, Xt, CHW, (long)CC*CHW, CC, (long)XTROWS*CC, 1, bx, by, bz,
             sbuf, Vb);
  } else {
    int i = id - 1024;
    int bx = i & 15, b = i >> 4;
    float* z = (float*)sbuf;
    z[t] = zl[b*CC + t];
    __syncthreads();
    int m = bx*256 + t;
    const float* base = img + (long)b*CC*CHW + m;
    float s = 0.f;
    for (int c = 0; c < CC; c++) s += base[(long)c*CHW] * z[c];
    heat[b*CHW + m] = s;
    out_img[(long)b*257*CHW + (long)256*CHW + m] = s;
  }
}

// ---------------- K3: NMS + top-150 (bitonic, value desc / index asc) --------
__global__ __launch_bounds__(1024) void topk_k(const float* __restrict__ heat,
                                               int* __restrict__ qids,
                                               float* __restrict__ out_coords){
  int b = blockIdx.x, t = threadIdx.x;
  __shared__ unsigned long long sk[4096];
  const float* hb = heat + (long)b*CHW;
  for (int p = t; p < 4096; p += 1024){
    int i = p >> 6, j = p & 63;
    float h = hb[p];
    bool ismax = false;
    if (i >= 1 && i < 63 && j >= 1 && j < 63){
      ismax = (h >= hb[p+64]) && (h > hb[p-64]) && (h >= hb[p+1]) && (h > hb[p-1]);
    }
    float sup = ismax ? h : (h - 1e9f);
    unsigned u = __float_as_uint(sup);
    u = (u & 0x80000000u) ? ~u : (u | 0x80000000u);
    unsigned long long key = ((unsigned long long)u << 32) | (unsigned)(0xFFFFFFFFu - (unsigned)p);
    sk[p] = ~key;                       // ascending sort of ~key == desired order
  }
  __syncthreads();
  for (int k = 2; k <= 4096; k <<= 1){
    for (int j = k >> 1; j > 0; j >>= 1){
      for (int tt = t; tt < 2048; tt += 1024){
        int i1 = 2*tt - (tt & (j-1));
        int i2 = i1 + j;
        unsigned long long a = sk[i1], c = sk[i2];
        bool up = ((i1 & k) == 0);
        if (up ? (a > c) : (a < c)){ sk[i1] = c; sk[i2] = a; }
      }
      __syncthreads();
    }
  }
  if (t < NQP){
    unsigned long long key = ~sk[t];
    int p = (int)(0xFFFFFFFFu - (unsigned)(key & 0xFFFFFFFFull));
    qids[b*160 + t] = p;
    out_coords[((long)b*NQP + t)*2 + 0] = (float)(p >> 6);
    out_coords[((long)b*NQP + t)*2 + 1] = (float)(p & 63);
  }
}

// ---------------- K4: MFMA flash attention, KV-SPLIT x2 ----------------------
// 512 blocks x 8 waves: block (b, m-tile, half) processes HALF the KV tiles.
// Single-buffered LDS 78,848B -> 2 blocks/CU -> 16 waves/CU (4/SIMD): the
// single-buffer stage drain is covered by the co-resident block's compute.
// Writes UN-NORMALIZED partial O + (m,l); mrg_k does the decode-merge + Wv
// projection + epilogue. XCD maps 1:1 to (b,half): K/V slice ~2.2MB L2-fit.
__global__ __launch_bounds__(512, 2) void flash_k(
    const u16* __restrict__ Xt, const u16* __restrict__ St,
    const u16* __restrict__ Vb, const float* __restrict__ maskp,
    float* __restrict__ Opart, float* __restrict__ MLpart){
  // LDS carve (78,848 B):
  //   [0,32768)      kp   u16[64][256] : K tile; Q round-trip; Tsum
  //   [32768,65536)  kt   u16[256][64] : V^T tile
  //   [65536,73728)  p    u16[64][64]  : P tile (per-wave private)
  //   [73728,77824)  maskb u8[4096]
  //   [77824,78848)  mlx  f32[4][2][16][2]
  __shared__ __align__(16) char smem[78848];
  u16*   kp = (u16*)smem;
  u16*   kt = (u16*)(smem + 32768);
  u16*   p_tile = (u16*)(smem + 65536);
  unsigned char* maskb = (unsigned char*)(smem + 73728);
  float* mlx = (float*)(smem + 77824);

  // XCD mapping: xcd = f&7 = b*2+half (one (b,half) per XCD); m-tile = f>>3
  int f = blockIdx.x;
  int b = (f & 7) >> 1;
  int half = f & 1;
  int mt = f >> 3;
  int m0 = mt*64;
  int ntBeg = half ? 33 : 0;
  int ntEnd = half ? 65 : 33;
  int pid = (b*64 + mt)*2 + half;

  int t = threadIdx.x;
  int lane = t & 63, l15 = lane & 15, qd = lane >> 4;
  int w = t >> 6, wm = w & 3, wn = w >> 2;
  f32x4 zero4 = {0.f,0.f,0.f,0.f};

  // ---- stage mask row into LDS as packed u8 (512 thr x 8 px) ----
  {
    const float* mp = maskp + (long)b*CHW + t*8;
    f32x4 a0 = *(const f32x4*)mp;
    f32x4 a1 = *(const f32x4*)(mp + 4);
    unsigned long long pk = 0;
    #pragma unroll
    for (int e = 0; e < 4; e++){
      pk |= (unsigned long long)(a0[e] == 1.0f ? 1u : 0u) << (8*e);
      pk |= (unsigned long long)(a1[e] == 1.0f ? 1u : 0u) << (8*(e+4));
    }
    *(unsigned long long*)&maskb[t*8] = pk;
  }

  const u16* xtb = Xt + (size_t)b*XTROWS*CC;
  const u16* vbb = Vb + (size_t)b*CC*VROW;

  // ---- Phase 0: Q[64][256] = Xrows · St^T (Xt group-swizzled: XOR addr) ----
  {
    f32x4 D[8];
    #pragma unroll
    for (int i = 0; i < 8; i++) D[i] = zero4;
    const u16* arow = xtb + (long)(m0 + wm*16 + l15)*CC;
    int rsw = (l15 & 7)*4;
    #pragma unroll
    for (int ks = 0; ks < 8; ks++){
      u16x8 af = *(const u16x8*)(arow + ((ks*4 + qd) ^ rsw)*8);
      #pragma unroll
      for (int ds = 0; ds < 8; ds++){
        int dsg = wn*8 + ds;
        u16x8 bf_ = *(const u16x8*)(St + (long)(dsg*16 + l15)*CC + ks*32 + qd*8);
        D[ds] = mfma16(af, bf_, D[ds]);
      }
    }
    #pragma unroll
    for (int ds = 0; ds < 8; ds++){
      #pragma unroll
      for (int r = 0; r < 4; r++){
        int prow = wm*16 + qd*4 + r;
        int ccol = (wn*8 + ds)*16 + l15;
        kp[prow*256 + ((ccol >> 3) ^ ((prow & 7)*4))*8 + (ccol & 7)] = f2b(D[ds][r]);
      }
    }
  }
  __syncthreads();
  u16x8 afrag[8];
  {
    int arl = wm*16 + l15;
    #pragma unroll
    for (int ks = 0; ks < 8; ks++)
      afrag[ks] = *(const u16x8*)&kp[arl*256 + (((ks*4 + qd)) ^ ((arl & 7)*4))*8];
  }
  int rowAllowed[4];
  float mi[4], li[4];
  #pragma unroll
  for (int r = 0; r < 4; r++){
    int m = m0 + wm*16 + qd*4 + r;
    rowAllowed[r] = maskb[m];
    mi[r] = -1e30f; li[r] = 0.f;
  }
  f32x4 O[16];
  #pragma unroll
  for (int i = 0; i < 16; i++) O[i] = zero4;
  __syncthreads();   // afrag reads done before staging overwrites kp

#define STAGE(n0_) do { \
    const u16* ksrc_ = xtb + (long)(n0_)*CC + w*2048 + lane*8; \
    u16* kl_ = kp + w*2048; \
    glds16(ksrc_,        kl_); \
    glds16(ksrc_ + 512,  kl_ + 512); \
    glds16(ksrc_ + 1024, kl_ + 1024); \
    glds16(ksrc_ + 1536, kl_ + 1536); \
    const u16* vsrc_ = vbb + (long)(w*32 + (lane >> 3))*VROW + (n0_) + (lane & 7)*8; \
    u16* vl_ = kt + w*2048; \
    glds16(vsrc_,            vl_); \
    glds16(vsrc_ + 8*VROW,   vl_ + 512); \
    glds16(vsrc_ + 16*VROW,  vl_ + 1024); \
    glds16(vsrc_ + 24*VROW,  vl_ + 1536); \
  } while(0)

  STAGE(ntBeg*64);
  __syncthreads();   // drains vmcnt -> first tile ready

  for (int nt = ntBeg; nt < ntEnd; nt++){
    int n0 = nt*64;

    // ---- QK^T (this wave's 32-column half) ----
    f32x4 sc[2];
    sc[0] = zero4; sc[1] = zero4;
    __builtin_amdgcn_s_setprio(1);
    #pragma unroll
    for (int ks = 0; ks < 8; ks++){
      #pragma unroll
      for (int ns = 0; ns < 2; ns++){
        int n_l = (wn*2 + ns)*16 + l15;
        u16x8 bfrag = *(const u16x8*)&kp[n_l*256 + (((ks*4 + qd)) ^ ((n_l & 7)*4))*8];
        sc[ns] = mfma16(afrag[ks], bfrag, sc[ns]);
      }
    }
    __builtin_amdgcn_s_setprio(0);

    // ---- mask bias + online softmax (wave-local, own half) ----
    float sEff[2][4];
    #pragma unroll
    for (int ns = 0; ns < 2; ns++){
      int n = n0 + (wn*2 + ns)*16 + l15;
      bool inv = (n >= CNQ);
      bool isEx = (n == CHW);
      int cm = 0;
      if (!inv && !isEx) cm = maskb[n];
      #pragma unroll
      for (int r = 0; r < 4; r++){
        float s = sc[ns][r];
        float se;
        if (inv)        se = -1e30f;
        else if (isEx)  se = s;
        else            se = (rowAllowed[r] & cm) ? s : s - 1e9f;
        sEff[ns][r] = se;
      }
    }
    float al[4], nm[4];
    #pragma unroll
    for (int r = 0; r < 4; r++){
      float tm = red16_max(fmaxf(sEff[0][r], sEff[1][r]));
      float newm = fmaxf(mi[r], tm);
      al[r] = (mi[r] < -1e29f) ? 0.f : __expf(fmaxf(mi[r] - newm, -88.f));
      nm[r] = newm; mi[r] = newm;
    }
    #pragma unroll
    for (int r = 0; r < 4; r++){
      float rs = 0.f;
      int prow = wm*16 + qd*4 + r;
      #pragma unroll
      for (int ns = 0; ns < 2; ns++){
        float p = __expf(fmaxf(sEff[ns][r] - nm[r], -88.f));
        rs += p;
        int ccol = (wn*2 + ns)*16 + l15;
        p_tile[prow*64 + ((ccol >> 3) ^ (prow & 7))*8 + (ccol & 7)] = f2b(p);
      }
      li[r] = li[r]*al[r] + red16_sum(rs);
    }
    // P writes/reads are wave-private regions: no barrier, just drain LDS.
    asm volatile("s_waitcnt lgkmcnt(0)" ::: "memory");

    // ---- rescale T only when the running max actually moved (al!=1) ----
    int needre = (al[0] != 1.f) | (al[1] != 1.f) | (al[2] != 1.f) | (al[3] != 1.f);
    if (__any(needre)){
      #pragma unroll
      for (int ds = 0; ds < 16; ds++){
        #pragma unroll
        for (int r = 0; r < 4; r++) O[ds][r] *= al[r];
      }
    }
    // ---- T += P·Vtile over this wave's 32-column half ----
    {
      int prow2 = wm*16 + l15;
      u16x8 pf = *(const u16x8*)&p_tile[prow2*64 + (((wn*4 + qd)) ^ (prow2 & 7))*8];
      __builtin_amdgcn_s_setprio(1);
      #pragma unroll
      for (int ds = 0; ds < 16; ds++){
        int c = ds*16 + l15;
        u16x8 vf = *(const u16x8*)&kt[c*64 + (((wn*4 + qd)) ^ (c & 7))*8];
        O[ds] = mfma16(pf, vf, O[ds]);
      }
      __builtin_amdgcn_s_setprio(0);
    }
    __syncthreads();   // all LDS reads of this tile done
    if (nt + 1 < ntEnd) STAGE((nt + 1)*64);
    __syncthreads();   // vmcnt drained -> next tile ready (drain covered by co-block)
  }
#undef STAGE

  // ---- in-block wn merge -> UN-NORMALIZED partial (m,l,O) ----
  if (l15 == 0){
    #pragma unroll
    for (int r = 0; r < 4; r++){
      mlx[(((wm*2 + wn)*16) + qd*4 + r)*2 + 0] = mi[r];
      mlx[(((wm*2 + wn)*16) + qd*4 + r)*2 + 1] = li[r];
    }
  }
  __syncthreads();
  float alpha[4], msv[4], lsv[4];
  #pragma unroll
  for (int r = 0; r < 4; r++){
    float mo = mlx[(((wm*2 + (1 - wn))*16) + qd*4 + r)*2 + 0];
    float lo = mlx[(((wm*2 + (1 - wn))*16) + qd*4 + r)*2 + 1];
    float ms = fmaxf(mi[r], mo);
    float aS = (mi[r] < -1e29f) ? 0.f : __expf(mi[r] - ms);
    float aO = (mo    < -1e29f) ? 0.f : __expf(mo - ms);
    lsv[r] = li[r]*aS + lo*aO;
    msv[r] = ms;
    alpha[r] = aS;
  }
  float* Tsum = (float*)smem;         // 64KB f32 scratch spanning kp+kt
  if (wn == 1){
    #pragma unroll
    for (int ds = 0; ds < 16; ds++){
      #pragma unroll
      for (int r = 0; r < 4; r++)
        Tsum[(wm*16 + qd*4 + r)*256 + ds*16 + l15] = O[ds][r]*alpha[r];
    }
  }
  __syncthreads();
  if (wn == 0){
    float* ob = Opart + (size_t)pid*64*256;
    #pragma unroll
    for (int ds = 0; ds < 16; ds++){
      #pragma unroll
      for (int r = 0; r < 4; r++){
        int row = wm*16 + qd*4 + r;
        float v = O[ds][r]*alpha[r] + Tsum[row*256 + ds*16 + l15];
        ob[row*256 + ds*16 + l15] = v;
      }
    }
    if (l15 == 0){
      #pragma unroll
      for (int r = 0; r < 4; r++){
        int row = wm*16 + qd*4 + r;
        MLpart[(size_t)pid*128 + row*2 + 0] = msv[r];
        MLpart[(size_t)pid*128 + row*2 + 1] = lsv[r];
      }
    }
  }
}

// ---------------- K4b: decode-merge + Wv projection + img epilogue -----------
// 256 blocks x 4 waves: combine the two KV halves, normalize, bf16 round-trip
// via LDS, F = T·Wv^T MFMA, add img, write out_img.
__global__ __launch_bounds__(256) void mrg_k(
    const float* __restrict__ Opart, const float* __restrict__ MLpart,
    const float* __restrict__ imgf, const float* __restrict__ Wv,
    float* __restrict__ out_img){
  __shared__ __align__(16) u16 kp[64*256];
  int id = blockIdx.x;                 // b*64 + mt
  int b = id >> 6;
  int m0 = (id & 63)*64;
  int t = threadIdx.x;
  int lane = t & 63, l15 = lane & 15, qd = lane >> 4;
  int wm = t >> 6;
  const float* O0 = Opart + (size_t)(id*2 + 0)*64*256;
  const float* O1 = Opart + (size_t)(id*2 + 1)*64*256;
  const float* ml0 = MLpart + (size_t)(id*2 + 0)*128;
  const float* ml1 = MLpart + (size_t)(id*2 + 1)*128;
  float a0[4], a1[4], linv[4];
  #pragma unroll
  for (int r = 0; r < 4; r++){
    int row = wm*16 + qd*4 + r;
    float m0v = ml0[row*2], l0 = ml0[row*2 + 1];
    float m1v = ml1[row*2], l1 = ml1[row*2 + 1];
    float ms = fmaxf(m0v, m1v);
    float e0 = (m0v < -1e29f) ? 0.f : __expf(m0v - ms);
    float e1 = (m1v < -1e29f) ? 0.f : __expf(m1v - ms);
    float l = l0*e0 + l1*e1;
    a0[r] = e0; a1[r] = e1;
    linv[r] = (l > 0.f) ? (1.0f / l) : 0.f;
  }
  #pragma unroll
  for (int ds = 0; ds < 16; ds++){
    #pragma unroll
    for (int r = 0; r < 4; r++){
      int row = wm*16 + qd*4 + r;
      int col = ds*16 + l15;
      float v = (O0[row*256 + col]*a0[r] + O1[row*256 + col]*a1[r]) * linv[r];
      kp[row*256 + ((col >> 3) ^ ((row & 7)*4))*8 + (col & 7)] = f2b(v);
    }
  }
  __syncthreads();
  u16x8 tfrag[8];
  {
    int arl = wm*16 + l15;
    #pragma unroll
    for (int ks = 0; ks < 8; ks++)
      tfrag[ks] = *(const u16x8*)&kp[arl*256 + (((ks*4 + qd)) ^ ((arl & 7)*4))*8];
  }
  f32x4 F[16];
  f32x4 zero4 = {0.f,0.f,0.f,0.f};
  #pragma unroll
  for (int i = 0; i < 16; i++) F[i] = zero4;
  #pragma unroll
  for (int ks = 0; ks < 8; ks++){
    #pragma unroll
    for (int ds = 0; ds < 16; ds++){
      const float* wr = Wv + (long)(ds*16 + l15)*CC + ks*32 + qd*8;
      f32x4 w0 = *(const f32x4*)wr;
      f32x4 w1 = *(const f32x4*)(wr + 4);
      F[ds] = mfma16(tfrag[ks], cvt8(w0, w1), F[ds]);
    }
  }
  float* oi = out_img + (long)b*257*CHW;
  const float* fi = imgf + (long)b*CC*CHW;
  int mb = m0 + wm*16 + qd*4;
  #pragma unroll
  for (int ds = 0; ds < 16; ds++){
    int d = ds*16 + l15;
    f32x4 ivals = *(const f32x4*)(fi + (long)d*CHW + mb);
    f32x4 ovals;
    #pragma unroll
    for (int r = 0; r < 4; r++) ovals[r] = F[ds][r] + ivals[r];
    *(f32x4*)(oi + (long)d*CHW + mb) = ovals;
  }
}

// ---------------- K5a: gather + LN + layer1 chunk (broadcast GEMV) -----------
__global__ __launch_bounds__(256) void qhead1_k(const float* __restrict__ out_img,
    const int* __restrict__ qids,
    const float* __restrict__ g, const float* __restrict__ be,
    const float* __restrict__ W1t, const float* __restrict__ b1,
    float* __restrict__ Hb){
  int hc = blockIdx.x, rb = blockIdx.y;
  int t = threadIdx.x, lane = t & 63, wv = t >> 6;
  __shared__ __align__(16) float xl[4][260];
  {
    int gq = rb*4 + wv;
    int b = gq / NQP, q = gq - b*NQP;
    int m = qids[b*160 + q];
    const float* oib = out_img + (long)b*257*CHW + m;
    float v[4];
    #pragma unroll
    for (int j = 0; j < 4; j++) v[j] = oib[(long)(lane + j*64)*CHW];
    float v4 = (lane == 0) ? oib[(long)256*CHW] : 0.f;
    float s = v[0]+v[1]+v[2]+v[3]+v4;
    #pragma unroll
    for (int d = 1; d < 64; d <<= 1) s += __shfl_xor(s, d, 64);
    float mu = s / 257.f;
    float d4 = (lane == 0) ? (v4 - mu) : 0.f;
    float vs = d4*d4;
    #pragma unroll
    for (int j = 0; j < 4; j++){ float dd = v[j]-mu; vs += dd*dd; }
    #pragma unroll
    for (int d = 1; d < 64; d <<= 1) vs += __shfl_xor(vs, d, 64);
    float inv = 1.0f / sqrtf(vs/257.f + 1e-5f);
    #pragma unroll
    for (int j = 0; j < 4; j++)
      xl[wv][lane + j*64] = (v[j]-mu)*inv*g[lane + j*64] + be[lane + j*64];
    if (lane == 0) xl[wv][256] = d4*inv*g[256] + be[256];
  }
  __syncthreads();
  int h = hc*256 + t;
  float acc0=0.f, acc1=0.f, acc2=0.f, acc3=0.f;
  #pragma unroll 8
  for (int c = 0; c < 256; c++){
    float wv_ = W1t[(long)c*CHID + h];
    acc0 += wv_*xl[0][c]; acc1 += wv_*xl[1][c];
    acc2 += wv_*xl[2][c]; acc3 += wv_*xl[3][c];
  }
  {
    float wv_ = W1t[(long)256*CHID + h];
    acc0 += wv_*xl[0][256]; acc1 += wv_*xl[1][256];
    acc2 += wv_*xl[2][256]; acc3 += wv_*xl[3][256];
  }
  float bb = b1[h];
  float* hb = Hb + (long)rb*4*CHID + h;
  hb[0]       = fmaxf(acc0 + bb, 0.f);
  hb[CHID]    = fmaxf(acc1 + bb, 0.f);
  hb[2*CHID]  = fmaxf(acc2 + bb, 0.f);
  hb[3*CHID]  = fmaxf(acc3 + bb, 0.f);
}

// ---------------- K5b: layer2 (broadcast GEMV, coalesced W2t) ----------------
__global__ __launch_bounds__(256) void qhead2_k(float* __restrict__ qbuf,
    const float* __restrict__ Hb, const float* __restrict__ W2t,
    const float* __restrict__ b2){
  int rb = blockIdx.x;
  int t = threadIdx.x, lane = t & 63, wv = t >> 6;
  __shared__ __align__(16) float hl[4][CHID];
  const float* hs = Hb + (long)rb*4*CHID;
  #pragma unroll
  for (int q = 0; q < 4; q++)
    *(f32x4*)&hl[q][t*4] = *(const f32x4*)&hs[(long)q*CHID + t*4];
  __syncthreads();
  float a0=0.f, a1=0.f, a2=0.f, a3=0.f;
  #pragma unroll 8
  for (int c = 0; c < CHID; c++){
    float wv_ = W2t[(long)c*257 + t];
    a0 += wv_*hl[0][c]; a1 += wv_*hl[1][c];
    a2 += wv_*hl[2][c]; a3 += wv_*hl[3][c];
  }
  float bb = b2[t];
  qbuf[(long)(rb*4 + 0)*257 + t] = a0 + bb;
  qbuf[(long)(rb*4 + 1)*257 + t] = a1 + bb;
  qbuf[(long)(rb*4 + 2)*257 + t] = a2 + bb;
  qbuf[(long)(rb*4 + 3)*257 + t] = a3 + bb;
  if (wv == 0){
    float p0=0.f, p1=0.f, p2=0.f, p3=0.f;
    #pragma unroll
    for (int k = 0; k < 16; k++){
      int c = lane*16 + k;
      float wv_ = W2t[(long)c*257 + 256];
      p0 += wv_*hl[0][c]; p1 += wv_*hl[1][c];
      p2 += wv_*hl[2][c]; p3 += wv_*hl[3][c];
    }
    #pragma unroll
    for (int d = 1; d < 64; d <<= 1){
      p0 += __shfl_xor(p0, d, 64); p1 += __shfl_xor(p1, d, 64);
      p2 += __shfl_xor(p2, d, 64); p3 += __shfl_xor(p3, d, 64);
    }
    if (lane == 0){
      float b256 = b2[256];
      qbuf[(long)(rb*4 + 0)*257 + 256] = p0 + b256;
      qbuf[(long)(rb*4 + 1)*257 + 256] = p1 + b256;
      qbuf[(long)(rb*4 + 2)*257 + 256] = p2 + b256;
      qbuf[(long)(rb*4 + 3)*257 + 256] = p3 + b256;
    }
  }
}

// ---------------- launch: input mapping by SIZE (robust to ordering) ---------
extern "C" void kernel_launch(void* const* d_in, const int* in_sizes, int n_in,
                              void* d_out, int out_size, void* d_ws, size_t ws_size,
                              hipStream_t stream){
  (void)out_size; (void)ws_size;
  int idxImg=-1, idxExe=-1, idxMask=-1, idxB1=-1;
  int idx65[2]={-1,-1}; int n65=0;
  int idx263[2]={-1,-1}; int n263=0;
  int idx257[3]={-1,-1,-1}; int n257=0;
  for (int i = 0; i < n_in; i++){
    int s = in_sizes[i];
    if      (s == 4194304) idxImg = i;
    else if (s == 50176)   idxExe = i;
    else if (s == 16384)   idxMask = i;
    else if (s == 1024)    idxB1 = i;
    else if (s == 65536)  { if (n65 < 2)  idx65[n65++] = i; }
    else if (s == 263168) { if (n263 < 2) idx263[n263++] = i; }
    else if (s == 257)    { if (n257 < 3) idx257[n257++] = i; }
  }
  const float* img  = (const float*)d_in[idxImg];
  const float* exe  = (const float*)d_in[idxExe];
  const float* mask = (const float*)d_in[idxMask];
  const float* S    = (const float*)d_in[idx65[0]];   // S before Wv in both dict & sorted order
  const float* Wv   = (const float*)d_in[idx65[1]];
  const float* W1   = (const float*)d_in[idx263[0]];  // W1 before W2 in both orders
  const float* W2   = (const float*)d_in[idx263[1]];
  const float* b1   = (const float*)d_in[idxB1];
  const float *lng, *lnb, *b2;
  if (idxImg == 0){           // dict order: ln_g, ln_b, b2
    lng = (const float*)d_in[idx257[0]];
    lnb = (const float*)d_in[idx257[1]];
    b2  = (const float*)d_in[idx257[2]];
  } else {                    // name-sorted: b2, ln_b, ln_g
    b2  = (const float*)d_in[idx257[0]];
    lnb = (const float*)d_in[idx257[1]];
    lng = (const float*)d_in[idx257[2]];
  }

  char* ws = (char*)d_ws;
  u16*   Xt   = (u16*)(ws + XT_OFF);
  u16*   Vb   = (u16*)(ws + VB_OFF);
  u16*   St   = (u16*)(ws + ST_OFF);
  float* zl   = (float*)(ws + ZL_OFF);
  float* heat = (float*)(ws + HEAT_OFF);
  int*   qids = (int*)(ws + QID_OFF);
  float* W1t  = (float*)(ws + W1T_OFF);
  float* W2t  = (float*)(ws + W2T_OFF);
  float* Hb   = (float*)(ws + HB_OFF);
  float* Op   = (float*)(ws + OP_OFF);
  float* Ml   = (float*)(ws + ML_OFF);

  float* out      = (float*)d_out;                       // f32 outputs
  float* out_img  = out;                                 // [4][257][4096]
  float* qbuf     = out + (size_t)CB*257*CHW;            // [4][150][257]
  float* out_crd  = qbuf + (size_t)CB*NQP*257;           // [4][150][2]

  prep_k<<<dim3(596), dim3(256), 0, stream>>>(
      exe, S, W1, W2, zl, Xt, Vb, St, W1t, W2t);
  big_k<<<dim3(1088), dim3(256), 0, stream>>>(
      img, zl, Xt, Vb, heat, out_img);
  topk_k<<<dim3(CB), dim3(1024), 0, stream>>>(heat, qids, out_crd);
  flash_k<<<dim3(512), dim3(512), 0, stream>>>(
      Xt, St, Vb, mask, Op, Ml);
  mrg_k<<<dim3(256), dim3(256), 0, stream>>>(Op, Ml, img, Wv, out_img);
  qhead1_k<<<dim3(4, CB*NQP/4), dim3(256), 0, stream>>>(
      out_img, qids, lng, lnb, W1t, b1, Hb);
  qhead2_k<<<dim3(CB*NQP/4), dim3(256), 0, stream>>>(qbuf, Hb, W2t, b2);
}

// Round 15
// 400.358 us; speedup vs baseline: 1.1568x; 1.1568x over previous
//
#include <hip/hip_runtime.h>
#include <hip/hip_bf16.h>
#include <stdint.h>

typedef unsigned short u16;
typedef unsigned int u32;
typedef unsigned long long u64;
typedef __attribute__((ext_vector_type(8))) unsigned short u16x8;
typedef __attribute__((ext_vector_type(8))) short short8;
typedef __attribute__((ext_vector_type(4))) float f32x4;

#define CB   4
#define CC   256
#define CHW  4096
#define CNQ  4097
#define NQP  150
#define CHID 1024
#define XTROWS 4160   // 4096 img rows + exemplar + 63 zero pad (65 tiles of 64)
#define VROW   4160   // V cols padded to 65 tiles of 64

// ---------------- workspace layout (bytes) ----------------
#define XT_OFF   0ul                                        // bf16 [B][4160][256] swizzled
#define VB_OFF   (XT_OFF  + (size_t)CB*XTROWS*CC*2)         // bf16 [B][256][4160] swizzled
#define ST_OFF   (VB_OFF  + (size_t)CB*CC*VROW*2)           // bf16 [256][256] (S^T)
#define EXE_OFF  (ST_OFF  + 131072ul)                       // f32  [B][256] (unused slot)
#define ZL_OFF   (EXE_OFF + 4096ul)                         // f32  [B][256]  (S·em)
#define HEAT_OFF (ZL_OFF  + 4096ul)                         // f32  [B][4096]
#define QID_OFF  (HEAT_OFF+ 65536ul)                        // int  [B][160]
#define W1T_OFF  (QID_OFF + 2560ul)                         // f32  [257][1024]
#define W2T_OFF  (W1T_OFF + 1052672ul)                      // f32  [1024][257]
#define HB_OFF   (W2T_OFF + 1052672ul)                      // f32  [600][1024]

__device__ __forceinline__ u16 f2b(float f){
  __hip_bfloat16 h = __float2bfloat16(f); u16 r; __builtin_memcpy(&r, &h, 2); return r;
}
__device__ __forceinline__ f32x4 mfma16(u16x8 a, u16x8 b, f32x4 c){
  short8 as, bs; __builtin_memcpy(&as, &a, 16); __builtin_memcpy(&bs, &b, 16);
  return __builtin_amdgcn_mfma_f32_16x16x32_bf16(as, bs, c, 0, 0, 0);
}
__device__ __forceinline__ u16x8 zero8(){
  u16x8 v;
  #pragma unroll
  for (int e = 0; e < 8; e++) v[e] = 0;
  return v;
}
__device__ __forceinline__ u16x8 cvt8(f32x4 a, f32x4 b){
  u16x8 v;
  v[0]=f2b(a[0]); v[1]=f2b(a[1]); v[2]=f2b(a[2]); v[3]=f2b(a[3]);
  v[4]=f2b(b[0]); v[5]=f2b(b[1]); v[6]=f2b(b[2]); v[7]=f2b(b[3]);
  return v;
}
// async global->LDS, 16B per lane; LDS dest = wave-uniform base + lane*16
__device__ __forceinline__ void glds16(const u16* gp, u16* lp){
  __builtin_amdgcn_global_load_lds(
      (const __attribute__((address_space(1))) u32*)gp,
      (__attribute__((address_space(3))) u32*)lp, 16, 0, 0);
}

// ---- 16-lane reduce, pure-VALU DPP (row=16 lanes matches l15 groups) ----
#define DPPF(x, ctrl) __int_as_float(__builtin_amdgcn_mov_dpp(__float_as_int(x), (ctrl), 0xF, 0xF, true))
__device__ __forceinline__ float red16_max(float x){
  x = fmaxf(x, DPPF(x, 0xB1));   // quad_perm xor1
  x = fmaxf(x, DPPF(x, 0x4E));   // quad_perm xor2
  x = fmaxf(x, DPPF(x, 0x141));  // row_half_mirror
  x = fmaxf(x, DPPF(x, 0x140));  // row_mirror
  return x;
}
__device__ __forceinline__ float red16_sum(float x){
  x += DPPF(x, 0xB1);
  x += DPPF(x, 0x4E);
  x += DPPF(x, 0x141);
  x += DPPF(x, 0x140);
  return x;
}

// ---------------- shared helper bodies (block-uniform branch safe) -----------
__device__ __forceinline__ void tpose_body(const float* __restrict__ src,
    float* __restrict__ dst, int R, int C, int bx, int by, char* sbuf){
  float (*tile)[33] = (float(*)[33])sbuf;
  int c0 = bx*32, r0 = by*32;
  int tc = threadIdx.x & 31, tr = threadIdx.x >> 5;   // 8 rows per pass
  for (int i = tr; i < 32; i += 8){
    int r = r0 + i, c = c0 + tc;
    tile[i][tc] = (r < R && c < C) ? src[(long)r*C + c] : 0.f;
  }
  __syncthreads();
  for (int i = tr; i < 32; i += 8){
    int c = c0 + i, r = r0 + tc;
    if (c < C && r < R) dst[(long)c*R + r] = tile[tc][i];
  }
}

// 64x64 tiled transpose, f32 src -> bf16 dst; swz=1 bakes flash's K XOR swizzle.
// If vb != nullptr, ALSO emits the row-major group-swizzled Vb span (vconv fuse).
__device__ __forceinline__ void t64_body(const float* __restrict__ src,
    u16* __restrict__ dst, int srcLd, long srcBatch, int dstLd, long dstBatch,
    int swz, int bx, int by, int bz, char* sbuf, u16* __restrict__ vb){
  u16 (*tile)[72] = (u16(*)[72])sbuf;
  int c0 = bx*64, m0 = by*64;
  const float* S = src + (long)bz*srcBatch;
  u16* D = dst + (long)bz*dstBatch;
  int t = threadIdx.x;
  int r = t >> 2, q = t & 3;
  for (int uu = q; uu < 8; uu += 4){
    const float* p = S + (long)(c0+r)*srcLd + m0 + uu*8;
    f32x4 a0 = *(const f32x4*)p;
    f32x4 a1 = *(const f32x4*)(p + 4);
    *(u16x8*)&tile[r][uu*8] = cvt8(a0, a1);
  }
  __syncthreads();
  for (int uu = q; uu < 8; uu += 4){
    u16x8 v;
    #pragma unroll
    for (int e = 0; e < 8; e++) v[e] = tile[uu*8 + e][r];
    int gidx = (c0 >> 3) + uu;
    if (swz) gidx ^= (r & 7)*4;
    *(u16x8*)(D + (long)(m0+r)*dstLd + gidx*8) = v;
  }
  if (vb){
    int c = c0 + r, cx = c & 7;
    u16* drow = vb + ((long)bz*CC + c)*VROW + m0;
    #pragma unroll
    for (int uu = q; uu < 8; uu += 4){
      u16x8 v = *(const u16x8*)&tile[r][uu*8];
      *(u16x8*)(drow + (uu ^ cx)*8) = v;
    }
  }
}

// ---------------- K0 (merged): exe-prep + W1t/W2t transposes + St ------------
__global__ __launch_bounds__(256) void prep_k(
    const float* __restrict__ exe, const float* __restrict__ S,
    const float* __restrict__ W1, const float* __restrict__ W2,
    float* __restrict__ zl, u16* __restrict__ Xt, u16* __restrict__ Vb,
    u16* __restrict__ St, float* __restrict__ W1t, float* __restrict__ W2t){
  __shared__ __align__(16) char sbuf[9216];
  int id = blockIdx.x, t = threadIdx.x;
  if (id < 4){
    float* em = (float*)sbuf;
    int b = id;
    const float* p = exe + (b*CC + t)*49;
    float s = 0.f;
    for (int i = 0; i < 49; i++) s += p[i];
    float m = s / 49.f;
    em[t] = m;
    u16* xb = Xt + (size_t)b*XTROWS*CC;
    xb[(size_t)CHW*CC + t] = f2b(m);        // exemplar row (row&7==0: no swizzle)
    for (int i = 0; i < 63; i++)            // zero pad rows 4097..4159
      xb[(size_t)(CHW + 1 + i)*CC + t] = 0;
    {
      int cx = t & 7;
      u16* drow = Vb + ((long)b*CC + t)*VROW;
      #pragma unroll
      for (int gl = 0; gl < 8; gl++)
        *(u16x8*)(drow + (512 + gl)*8) = zero8();
      drow[(512 + cx)*8] = f2b(m);
    }
    __syncthreads();
    const float* Sr = S + (long)t*CC;
    float z = 0.f;
    for (int d = 0; d < CC; d++) z += Sr[d] * em[d];
    zl[b*CC + t] = z;
  } else if (id < 292){
    int i = id - 4;
    tpose_body(W1, W1t, CHID, 257, i % 9, i / 9, sbuf);
  } else if (id < 580){
    int i = id - 292;
    tpose_body(W2, W2t, 257, CHID, i % 32, i / 32, sbuf);
  } else {
    int i = id - 580;
    t64_body(S, St, CC, 0, CC, 0, 0, i & 3, i >> 2, 0, sbuf, nullptr);
  }
}

// ---------------- K1 (merged): img->(Xt + Vb) fused transpose + heat2 --------
__global__ __launch_bounds__(256) void big_k(
    const float* __restrict__ img, const float* __restrict__ zl,
    u16* __restrict__ Xt, u16* __restrict__ Vb,
    float* __restrict__ heat, float* __restrict__ out_img){
  __shared__ __align__(16) char sbuf[9216];
  int id = blockIdx.x, t = threadIdx.x;
  if (id < 1024){
    int bx = id & 3, by = (id >> 2) & 63, bz = id >> 8;
    t64_body(img, Xt, CHW, (long)CC*CHW, CC, (long)XTROWS*CC, 1, bx, by, bz,
             sbuf, Vb);
  } else {
    int i = id - 1024;
    int bx = i & 15, b = i >> 4;
    float* z = (float*)sbuf;
    z[t] = zl[b*CC + t];
    __syncthreads();
    int m = bx*256 + t;
    const float* base = img + (long)b*CC*CHW + m;
    float s = 0.f;
    for (int c = 0; c < CC; c++) s += base[(long)c*CHW] * z[c];
    heat[b*CHW + m] = s;
    out_img[(long)b*257*CHW + (long)256*CHW + m] = s;
  }
}

// ---------------- K3: NMS + top-150 (bitonic, value desc / index asc) --------
__global__ __launch_bounds__(1024) void topk_k(const float* __restrict__ heat,
                                               int* __restrict__ qids,
                                               float* __restrict__ out_coords){
  int b = blockIdx.x, t = threadIdx.x;
  __shared__ unsigned long long sk[4096];
  const float* hb = heat + (long)b*CHW;
  for (int p = t; p < 4096; p += 1024){
    int i = p >> 6, j = p & 63;
    float h = hb[p];
    bool ismax = false;
    if (i >= 1 && i < 63 && j >= 1 && j < 63){
      ismax = (h >= hb[p+64]) && (h > hb[p-64]) && (h >= hb[p+1]) && (h > hb[p-1]);
    }
    float sup = ismax ? h : (h - 1e9f);
    unsigned u = __float_as_uint(sup);
    u = (u & 0x80000000u) ? ~u : (u | 0x80000000u);
    unsigned long long key = ((unsigned long long)u << 32) | (unsigned)(0xFFFFFFFFu - (unsigned)p);
    sk[p] = ~key;                       // ascending sort of ~key == desired order
  }
  __syncthreads();
  for (int k = 2; k <= 4096; k <<= 1){
    for (int j = k >> 1; j > 0; j >>= 1){
      for (int tt = t; tt < 2048; tt += 1024){
        int i1 = 2*tt - (tt & (j-1));
        int i2 = i1 + j;
        unsigned long long a = sk[i1], c = sk[i2];
        bool up = ((i1 & k) == 0);
        if (up ? (a > c) : (a < c)){ sk[i1] = c; sk[i2] = a; }
      }
      __syncthreads();
    }
  }
  if (t < NQP){
    unsigned long long key = ~sk[t];
    int p = (int)(0xFFFFFFFFu - (unsigned)(key & 0xFFFFFFFFull));
    qids[b*160 + t] = p;
    out_coords[((long)b*NQP + t)*2 + 0] = (float)(p >> 6);
    out_coords[((long)b*NQP + t)*2 + 1] = (float)(p & 63);
  }
}

// ---------------- K4: MFMA flash attention -----------------------------------
// 512 threads = 8 waves = 4 M x 2 N-halves; DPP softmax; double-buffered LDS +
// async glds16 staging; XCD-aware block swizzle (FETCH 80->27MB, time-neutral).
// Occupancy ladder closed: 8 waves/CU + this pipeline is the measured optimum
// (R1: 4->8 waves +78%; R7 indep-barrier null; R14 KV-split negative; R2 spill).
__global__ __launch_bounds__(512, 2) void flash_k(
    const u16* __restrict__ Xt, const u16* __restrict__ St,
    const u16* __restrict__ Vb, const float* __restrict__ imgf,
    const float* __restrict__ maskp, const float* __restrict__ Wv,
    float* __restrict__ out_img){
  __shared__ __align__(16) char smem[144384];
  u16*   kp0 = (u16*)smem;
  u16*   kt0 = (u16*)(smem + 32768);
  u16*   kp1 = (u16*)(smem + 65536);
  u16*   kt1 = (u16*)(smem + 98304);
  u16*   p_tile = (u16*)(smem + 131072);
  unsigned char* maskb = (unsigned char*)(smem + 139264);
  float* mlx = (float*)(smem + 143360);

  // bijective XCD swizzle: logical l = (f%8)*32 + f/8; b = l/64, mtile = l%64
  int f = blockIdx.x;
  int l = (f & 7)*32 + (f >> 3);
  int b = l >> 6;
  int m0 = (l & 63)*64;
  int t = threadIdx.x;
  int lane = t & 63, l15 = lane & 15, qd = lane >> 4;
  int w = t >> 6, wm = w & 3, wn = w >> 2;
  f32x4 zero4 = {0.f,0.f,0.f,0.f};

  // ---- stage mask row into LDS as packed u8 (512 thr x 8 px) ----
  {
    const float* mp = maskp + (long)b*CHW + t*8;
    f32x4 a0 = *(const f32x4*)mp;
    f32x4 a1 = *(const f32x4*)(mp + 4);
    unsigned long long pk = 0;
    #pragma unroll
    for (int e = 0; e < 4; e++){
      pk |= (unsigned long long)(a0[e] == 1.0f ? 1u : 0u) << (8*e);
      pk |= (unsigned long long)(a1[e] == 1.0f ? 1u : 0u) << (8*(e+4));
    }
    *(unsigned long long*)&maskb[t*8] = pk;
  }

  const u16* xtb = Xt + (size_t)b*XTROWS*CC;
  const u16* vbb = Vb + (size_t)b*CC*VROW;

  // ---- Phase 0: Q[64][256] = Xrows · St^T (Xt is group-swizzled: XOR addr) --
  {
    f32x4 D[8];
    #pragma unroll
    for (int i = 0; i < 8; i++) D[i] = zero4;
    const u16* arow = xtb + (long)(m0 + wm*16 + l15)*CC;
    int rsw = (l15 & 7)*4;
    #pragma unroll
    for (int ks = 0; ks < 8; ks++){
      u16x8 af = *(const u16x8*)(arow + ((ks*4 + qd) ^ rsw)*8);
      #pragma unroll
      for (int ds = 0; ds < 8; ds++){
        int dsg = wn*8 + ds;
        u16x8 bf_ = *(const u16x8*)(St + (long)(dsg*16 + l15)*CC + ks*32 + qd*8);
        D[ds] = mfma16(af, bf_, D[ds]);
      }
    }
    #pragma unroll
    for (int ds = 0; ds < 8; ds++){
      #pragma unroll
      for (int r = 0; r < 4; r++){
        int prow = wm*16 + qd*4 + r;
        int ccol = (wn*8 + ds)*16 + l15;
        kp0[prow*256 + ((ccol >> 3) ^ ((prow & 7)*4))*8 + (ccol & 7)] = f2b(D[ds][r]);
      }
    }
  }
  __syncthreads();
  u16x8 afrag[8];
  {
    int arl = wm*16 + l15;
    #pragma unroll
    for (int ks = 0; ks < 8; ks++)
      afrag[ks] = *(const u16x8*)&kp0[arl*256 + (((ks*4 + qd)) ^ ((arl & 7)*4))*8];
  }
  int rowAllowed[4];
  float mi[4], li[4];
  #pragma unroll
  for (int r = 0; r < 4; r++){
    int m = m0 + wm*16 + qd*4 + r;
    rowAllowed[r] = maskb[m];
    mi[r] = -1e30f; li[r] = 0.f;
  }
  f32x4 O[16];
  #pragma unroll
  for (int i = 0; i < 16; i++) O[i] = zero4;
  __syncthreads();   // afrag reads done before staging overwrites kp0

  // ---- prologue: async-stage tile 0 into buf0 ----
  {
    const u16* ksrc = xtb + w*2048 + lane*8;
    u16* kl = kp0 + w*2048;
    glds16(ksrc,        kl);
    glds16(ksrc + 512,  kl + 512);
    glds16(ksrc + 1024, kl + 1024);
    glds16(ksrc + 1536, kl + 1536);
    const u16* vsrc = vbb + (long)(w*32 + (lane >> 3))*VROW + (lane & 7)*8;
    u16* vl = kt0 + w*2048;
    glds16(vsrc,            vl);
    glds16(vsrc + 8*VROW,   vl + 512);
    glds16(vsrc + 16*VROW,  vl + 1024);
    glds16(vsrc + 24*VROW,  vl + 1536);
  }
  __syncthreads();   // drains vmcnt -> tile 0 ready

  for (int nt = 0; nt < 65; nt++){
    int cur = nt & 1;
    const u16* kpc = cur ? kp1 : kp0;
    const u16* ktc = cur ? kt1 : kt0;
    u16* kpn = cur ? kp0 : kp1;
    u16* ktn = cur ? kt0 : kt1;
    int n0 = nt*64;

    // ---- ISSUE next tile's async loads (fly during this tile's compute) ----
    if (nt < 64){
      int n1 = n0 + 64;
      const u16* ksrc = xtb + (long)n1*CC + w*2048 + lane*8;
      u16* kl = kpn + w*2048;
      glds16(ksrc,        kl);
      glds16(ksrc + 512,  kl + 512);
      glds16(ksrc + 1024, kl + 1024);
      glds16(ksrc + 1536, kl + 1536);
      const u16* vsrc = vbb + (long)(w*32 + (lane >> 3))*VROW + n1 + (lane & 7)*8;
      u16* vl = ktn + w*2048;
      glds16(vsrc,            vl);
      glds16(vsrc + 8*VROW,   vl + 512);
      glds16(vsrc + 16*VROW,  vl + 1024);
      glds16(vsrc + 24*VROW,  vl + 1536);
    }

    // ---- QK^T (this wave's 32-column half) on buf[cur] ----
    f32x4 sc[2];
    sc[0] = zero4; sc[1] = zero4;
    __builtin_amdgcn_s_setprio(1);
    #pragma unroll
    for (int ks = 0; ks < 8; ks++){
      #pragma unroll
      for (int ns = 0; ns < 2; ns++){
        int n_l = (wn*2 + ns)*16 + l15;
        u16x8 bfrag = *(const u16x8*)&kpc[n_l*256 + (((ks*4 + qd)) ^ ((n_l & 7)*4))*8];
        sc[ns] = mfma16(afrag[ks], bfrag, sc[ns]);
      }
    }
    __builtin_amdgcn_s_setprio(0);

    // ---- mask bias + online softmax (wave-local, own half) ----
    float sEff[2][4];
    #pragma unroll
    for (int ns = 0; ns < 2; ns++){
      int n = n0 + (wn*2 + ns)*16 + l15;
      bool inv = (n >= CNQ);
      bool isEx = (n == CHW);
      int cm = 0;
      if (!inv && !isEx) cm = maskb[n];
      #pragma unroll
      for (int r = 0; r < 4; r++){
        float s = sc[ns][r];
        float se;
        if (inv)        se = -1e30f;
        else if (isEx)  se = s;
        else            se = (rowAllowed[r] & cm) ? s : s - 1e9f;
        sEff[ns][r] = se;
      }
    }
    float al[4], nm[4];
    #pragma unroll
    for (int r = 0; r < 4; r++){
      float tm = red16_max(fmaxf(sEff[0][r], sEff[1][r]));
      float newm = fmaxf(mi[r], tm);
      al[r] = (mi[r] < -1e29f) ? 0.f : __expf(fmaxf(mi[r] - newm, -88.f));
      nm[r] = newm; mi[r] = newm;
    }
    #pragma unroll
    for (int r = 0; r < 4; r++){
      float rs = 0.f;
      int prow = wm*16 + qd*4 + r;
      #pragma unroll
      for (int ns = 0; ns < 2; ns++){
        float p = __expf(fmaxf(sEff[ns][r] - nm[r], -88.f));
        rs += p;
        int ccol = (wn*2 + ns)*16 + l15;
        p_tile[prow*64 + ((ccol >> 3) ^ (prow & 7))*8 + (ccol & 7)] = f2b(p);
      }
      li[r] = li[r]*al[r] + red16_sum(rs);
    }
    // P writes/reads are wave-private regions: no barrier, just drain LDS.
    asm volatile("s_waitcnt lgkmcnt(0)" ::: "memory");

    // ---- rescale T only when the running max actually moved (al!=1) ----
    int needre = (al[0] != 1.f) | (al[1] != 1.f) | (al[2] != 1.f) | (al[3] != 1.f);
    if (__any(needre)){
      #pragma unroll
      for (int ds = 0; ds < 16; ds++){
        #pragma unroll
        for (int r = 0; r < 4; r++) O[ds][r] *= al[r];
      }
    }
    // ---- T += P·Vtile over this wave's 32-column half ----
    {
      int prow2 = wm*16 + l15;
      u16x8 pf = *(const u16x8*)&p_tile[prow2*64 + (((wn*4 + qd)) ^ (prow2 & 7))*8];
      __builtin_amdgcn_s_setprio(1);
      #pragma unroll
      for (int ds = 0; ds < 16; ds++){
        int c = ds*16 + l15;
        u16x8 vf = *(const u16x8*)&ktc[c*64 + (((wn*4 + qd)) ^ (c & 7))*8];
        O[ds] = mfma16(pf, vf, O[ds]);
      }
      __builtin_amdgcn_s_setprio(0);
    }
    __syncthreads();   // buf[cur] reads done; drains vmcnt -> buf[cur^1] ready
  }

  // ---- merge the two N-halves (flash-decoding in-block merge) ----
  if (l15 == 0){
    #pragma unroll
    for (int r = 0; r < 4; r++){
      mlx[(((wm*2 + wn)*16) + qd*4 + r)*2 + 0] = mi[r];
      mlx[(((wm*2 + wn)*16) + qd*4 + r)*2 + 1] = li[r];
    }
  }
  __syncthreads();
  float alpha[4], linv[4];
  #pragma unroll
  for (int r = 0; r < 4; r++){
    float mo = mlx[(((wm*2 + (1 - wn))*16) + qd*4 + r)*2 + 0];
    float lo = mlx[(((wm*2 + (1 - wn))*16) + qd*4 + r)*2 + 1];
    float ms = fmaxf(mi[r], mo);
    float aS = (mi[r] < -1e29f) ? 0.f : __expf(mi[r] - ms);
    float aO = (mo    < -1e29f) ? 0.f : __expf(mo - ms);
    float ls = li[r]*aS + lo*aO;
    alpha[r] = aS;
    linv[r] = (ls > 0.f) ? (1.0f / ls) : 0.f;
  }
  float* Tsum = (float*)smem;         // 64KB f32 scratch spanning kp0+kt0
  if (wn == 1){
    #pragma unroll
    for (int ds = 0; ds < 16; ds++){
      #pragma unroll
      for (int r = 0; r < 4; r++)
        Tsum[(wm*16 + qd*4 + r)*256 + ds*16 + l15] = O[ds][r]*alpha[r];
    }
  }
  __syncthreads();
  if (wn == 0){
    #pragma unroll
    for (int ds = 0; ds < 16; ds++){
      #pragma unroll
      for (int r = 0; r < 4; r++)
        O[ds][r] = (O[ds][r]*alpha[r] + Tsum[(wm*16 + qd*4 + r)*256 + ds*16 + l15]) * linv[r];
    }
  }
  __syncthreads();                    // Tsum reads done before bf16 overwrite
  if (wn == 0){
    #pragma unroll
    for (int ds = 0; ds < 16; ds++){
      #pragma unroll
      for (int r = 0; r < 4; r++){
        int prow = wm*16 + qd*4 + r;
        int ccol = ds*16 + l15;
        kp0[prow*256 + ((ccol >> 3) ^ ((prow & 7)*4))*8 + (ccol & 7)] = f2b(O[ds][r]);
      }
    }
  }
  __syncthreads();
  u16x8 tfrag[8];
  {
    int arl = wm*16 + l15;
    #pragma unroll
    for (int ks = 0; ks < 8; ks++)
      tfrag[ks] = *(const u16x8*)&kp0[arl*256 + (((ks*4 + qd)) ^ ((arl & 7)*4))*8];
  }
  // ---- final projection F = T_norm · Wv^T, ds split between halves ----
  f32x4 F[8];
  #pragma unroll
  for (int i = 0; i < 8; i++) F[i] = zero4;
  #pragma unroll
  for (int ks = 0; ks < 8; ks++){
    #pragma unroll
    for (int ds = 0; ds < 8; ds++){
      int dsg = wn*8 + ds;
      const float* wr = Wv + (long)(dsg*16 + l15)*CC + ks*32 + qd*8;
      f32x4 w0 = *(const f32x4*)wr;
      f32x4 w1 = *(const f32x4*)(wr + 4);
      F[ds] = mfma16(tfrag[ks], cvt8(w0, w1), F[ds]);
    }
  }

  // ---- epilogue: f32 img_out only (query rows gathered by qhead1) ----
  float* oi = out_img + (long)b*257*CHW;
  const float* fi = imgf + (long)b*CC*CHW;
  int mb = m0 + wm*16 + qd*4;
  #pragma unroll
  for (int ds = 0; ds < 8; ds++){
    int d = (wn*8 + ds)*16 + l15;
    f32x4 ivals = *(const f32x4*)(fi + (long)d*CHW + mb);
    f32x4 ovals;
    #pragma unroll
    for (int r = 0; r < 4; r++) ovals[r] = F[ds][r] + ivals[r];
    *(f32x4*)(oi + (long)d*CHW + mb) = ovals;
  }
}

// ---------------- K5a: gather + LN + layer1 chunk (broadcast GEMV) -----------
// Rows gathered directly from out_img via qids (L2-cached across h-chunks;
// the separate gather_k pass measured +9us WORSE — do not re-split).
__global__ __launch_bounds__(256) void qhead1_k(const float* __restrict__ out_img,
    const int* __restrict__ qids,
    const float* __restrict__ g, const float* __restrict__ be,
    const float* __restrict__ W1t, const float* __restrict__ b1,
    float* __restrict__ Hb){
  int hc = blockIdx.x, rb = blockIdx.y;
  int t = threadIdx.x, lane = t & 63, wv = t >> 6;
  __shared__ __align__(16) float xl[4][260];
  // ---- gather + LN: wave wv handles global row rb*4+wv ----
  {
    int gq = rb*4 + wv;
    int b = gq / NQP, q = gq - b*NQP;
    int m = qids[b*160 + q];
    const float* oib = out_img + (long)b*257*CHW + m;
    float v[4];
    #pragma unroll
    for (int j = 0; j < 4; j++) v[j] = oib[(long)(lane + j*64)*CHW];
    float v4 = (lane == 0) ? oib[(long)256*CHW] : 0.f;
    float s = v[0]+v[1]+v[2]+v[3]+v4;
    #pragma unroll
    for (int d = 1; d < 64; d <<= 1) s += __shfl_xor(s, d, 64);
    float mu = s / 257.f;
    float d4 = (lane == 0) ? (v4 - mu) : 0.f;
    float vs = d4*d4;
    #pragma unroll
    for (int j = 0; j < 4; j++){ float dd = v[j]-mu; vs += dd*dd; }
    #pragma unroll
    for (int d = 1; d < 64; d <<= 1) vs += __shfl_xor(vs, d, 64);
    float inv = 1.0f / sqrtf(vs/257.f + 1e-5f);
    #pragma unroll
    for (int j = 0; j < 4; j++)
      xl[wv][lane + j*64] = (v[j]-mu)*inv*g[lane + j*64] + be[lane + j*64];
    if (lane == 0) xl[wv][256] = d4*inv*g[256] + be[256];
  }
  __syncthreads();
  int h = hc*256 + t;
  float acc0=0.f, acc1=0.f, acc2=0.f, acc3=0.f;
  #pragma unroll 8
  for (int c = 0; c < 256; c++){
    float wv_ = W1t[(long)c*CHID + h];
    acc0 += wv_*xl[0][c]; acc1 += wv_*xl[1][c];
    acc2 += wv_*xl[2][c]; acc3 += wv_*xl[3][c];
  }
  {
    float wv_ = W1t[(long)256*CHID + h];
    acc0 += wv_*xl[0][256]; acc1 += wv_*xl[1][256];
    acc2 += wv_*xl[2][256]; acc3 += wv_*xl[3][256];
  }
  float bb = b1[h];
  float* hb = Hb + (long)rb*4*CHID + h;
  hb[0]       = fmaxf(acc0 + bb, 0.f);
  hb[CHID]    = fmaxf(acc1 + bb, 0.f);
  hb[2*CHID]  = fmaxf(acc2 + bb, 0.f);
  hb[3*CHID]  = fmaxf(acc3 + bb, 0.f);
}

// ---------------- K5b: layer2 (broadcast GEMV, coalesced W2t) ----------------
__global__ __launch_bounds__(256) void qhead2_k(float* __restrict__ qbuf,
    const float* __restrict__ Hb, const float* __restrict__ W2t,
    const float* __restrict__ b2){
  int rb = blockIdx.x;
  int t = threadIdx.x, lane = t & 63, wv = t >> 6;
  __shared__ __align__(16) float hl[4][CHID];
  const float* hs = Hb + (long)rb*4*CHID;
  #pragma unroll
  for (int q = 0; q < 4; q++)
    *(f32x4*)&hl[q][t*4] = *(const f32x4*)&hs[(long)q*CHID + t*4];
  __syncthreads();
  float a0=0.f, a1=0.f, a2=0.f, a3=0.f;
  #pragma unroll 8
  for (int c = 0; c < CHID; c++){
    float wv_ = W2t[(long)c*257 + t];
    a0 += wv_*hl[0][c]; a1 += wv_*hl[1][c];
    a2 += wv_*hl[2][c]; a3 += wv_*hl[3][c];
  }
  float bb = b2[t];
  qbuf[(long)(rb*4 + 0)*257 + t] = a0 + bb;
  qbuf[(long)(rb*4 + 1)*257 + t] = a1 + bb;
  qbuf[(long)(rb*4 + 2)*257 + t] = a2 + bb;
  qbuf[(long)(rb*4 + 3)*257 + t] = a3 + bb;
  if (wv == 0){
    float p0=0.f, p1=0.f, p2=0.f, p3=0.f;
    #pragma unroll
    for (int k = 0; k < 16; k++){
      int c = lane*16 + k;
      float wv_ = W2t[(long)c*257 + 256];
      p0 += wv_*hl[0][c]; p1 += wv_*hl[1][c];
      p2 += wv_*hl[2][c]; p3 += wv_*hl[3][c];
    }
    #pragma unroll
    for (int d = 1; d < 64; d <<= 1){
      p0 += __shfl_xor(p0, d, 64); p1 += __shfl_xor(p1, d, 64);
      p2 += __shfl_xor(p2, d, 64); p3 += __shfl_xor(p3, d, 64);
    }
    if (lane == 0){
      float b256 = b2[256];
      qbuf[(long)(rb*4 + 0)*257 + 256] = p0 + b256;
      qbuf[(long)(rb*4 + 1)*257 + 256] = p1 + b256;
      qbuf[(long)(rb*4 + 2)*257 + 256] = p2 + b256;
      qbuf[(long)(rb*4 + 3)*257 + 256] = p3 + b256;
    }
  }
}

// ---------------- launch: input mapping by SIZE (robust to ordering) ---------
extern "C" void kernel_launch(void* const* d_in, const int* in_sizes, int n_in,
                              void* d_out, int out_size, void* d_ws, size_t ws_size,
                              hipStream_t stream){
  (void)out_size; (void)ws_size;
  int idxImg=-1, idxExe=-1, idxMask=-1, idxB1=-1;
  int idx65[2]={-1,-1}; int n65=0;
  int idx263[2]={-1,-1}; int n263=0;
  int idx257[3]={-1,-1,-1}; int n257=0;
  for (int i = 0; i < n_in; i++){
    int s = in_sizes[i];
    if      (s == 4194304) idxImg = i;
    else if (s == 50176)   idxExe = i;
    else if (s == 16384)   idxMask = i;
    else if (s == 1024)    idxB1 = i;
    else if (s == 65536)  { if (n65 < 2)  idx65[n65++] = i; }
    else if (s == 263168) { if (n263 < 2) idx263[n263++] = i; }
    else if (s == 257)    { if (n257 < 3) idx257[n257++] = i; }
  }
  const float* img  = (const float*)d_in[idxImg];
  const float* exe  = (const float*)d_in[idxExe];
  const float* mask = (const float*)d_in[idxMask];
  const float* S    = (const float*)d_in[idx65[0]];   // S before Wv in both dict & sorted order
  const float* Wv   = (const float*)d_in[idx65[1]];
  const float* W1   = (const float*)d_in[idx263[0]];  // W1 before W2 in both orders
  const float* W2   = (const float*)d_in[idx263[1]];
  const float* b1   = (const float*)d_in[idxB1];
  const float *lng, *lnb, *b2;
  if (idxImg == 0){           // dict order: ln_g, ln_b, b2
    lng = (const float*)d_in[idx257[0]];
    lnb = (const float*)d_in[idx257[1]];
    b2  = (const float*)d_in[idx257[2]];
  } else {                    // name-sorted: b2, ln_b, ln_g
    b2  = (const float*)d_in[idx257[0]];
    lnb = (const float*)d_in[idx257[1]];
    lng = (const float*)d_in[idx257[2]];
  }

  char* ws = (char*)d_ws;
  u16*   Xt   = (u16*)(ws + XT_OFF);
  u16*   Vb   = (u16*)(ws + VB_OFF);
  u16*   St   = (u16*)(ws + ST_OFF);
  float* zl   = (float*)(ws + ZL_OFF);
  float* heat = (float*)(ws + HEAT_OFF);
  int*   qids = (int*)(ws + QID_OFF);
  float* W1t  = (float*)(ws + W1T_OFF);
  float* W2t  = (float*)(ws + W2T_OFF);
  float* Hb   = (float*)(ws + HB_OFF);

  float* out      = (float*)d_out;                       // f32 outputs
  float* out_img  = out;                                 // [4][257][4096]
  float* qbuf     = out + (size_t)CB*257*CHW;            // [4][150][257]
  float* out_crd  = qbuf + (size_t)CB*NQP*257;           // [4][150][2]

  prep_k<<<dim3(596), dim3(256), 0, stream>>>(
      exe, S, W1, W2, zl, Xt, Vb, St, W1t, W2t);
  big_k<<<dim3(1088), dim3(256), 0, stream>>>(
      img, zl, Xt, Vb, heat, out_img);
  topk_k<<<dim3(CB), dim3(1024), 0, stream>>>(heat, qids, out_crd);
  flash_k<<<dim3(256), dim3(512), 0, stream>>>(
      Xt, St, Vb, img, mask, Wv, out_img);
  qhead1_k<<<dim3(4, CB*NQP/4), dim3(256), 0, stream>>>(
      out_img, qids, lng, lnb, W1t, b1, Hb);
  qhead2_k<<<dim3(CB*NQP/4), dim3(256), 0, stream>>>(qbuf, Hb, W2t, b2);
}